// Round 8
// baseline (104.569 us; speedup 1.0000x reference)
//
#include <hip/hip_runtime.h>
#include <stdint.h>

#define T_TOK 8192
#define DM    1024
#define NE    8
#define BOT   64
#define HD    512
#define PW    8
#define NPREP (T_TOK / PW)

// workspace offsets (bytes)
#define XB_OFF   0u
#define HC_OFF   16777216u
#define WDT_OFF  18874368u
#define WUT_OFF  19922944u
#define SG_OFF   20971520u
#define RT_OFF   21233664u
#define IDX_OFF  21266432u
#define SCL_OFF  21528576u
#define PL_OFF   21790720u
#define CNT_OFF  22708224u

typedef __attribute__((ext_vector_type(8))) short bf16x8;
typedef __attribute__((ext_vector_type(4))) short bf16x4;
typedef __attribute__((ext_vector_type(4))) float f32x4;

__device__ __forceinline__ ushort f2bf(float f) {
  union { float f; uint32_t u; } v; v.f = f;
  uint32_t r = (v.u + 0x7fffu + ((v.u >> 16) & 1u)) >> 16;
  return (ushort)r;
}

// ---- prep (blocks 0..1023): X->bf16, fp32 gating, top-2, route word --------
// ---- cvt  (blocks 1024..1279): WdT / WuT transposes ------------------------
__global__ __launch_bounds__(256, 2)
void prep_cvt_kernel(const float* __restrict__ x, const float* __restrict__ wg,
                     const float* __restrict__ Wd, const float* __restrict__ Wu,
                     ushort* __restrict__ Xb, float* __restrict__ sg,
                     int* __restrict__ route, ushort* __restrict__ WdT,
                     ushort* __restrict__ WuT, int* __restrict__ cntz) {
  __shared__ float part[4][PW][NE];
  __shared__ ushort tl[64][72];
  if (blockIdx.x < NPREP) {
    if (blockIdx.x == 0 && threadIdx.x < 36) cntz[threadIdx.x] = 0;  // cnt[8]+pcnt[28]
    const int lane = threadIdx.x & 63;
    const int w    = threadIdx.x >> 6;
    const int t0   = blockIdx.x * PW;
    const int dd   = w * 256 + lane * 4;
    float4 wgr[4][2];
    #pragma unroll
    for (int j = 0; j < 4; ++j) {
      wgr[j][0] = *(const float4*)(wg + (size_t)(dd + j) * NE);
      wgr[j][1] = *(const float4*)(wg + (size_t)(dd + j) * NE + 4);
    }
    const int ebit = ((lane & 1) << 2) | (lane & 2) | ((lane >> 2) & 1);
    const float* xp = x + (size_t)t0 * DM + dd;
    float4 xv = *(const float4*)xp;
    #pragma unroll
    for (int tk = 0; tk < PW; ++tk) {
      float4 nxt = {};
      if (tk + 1 < PW) nxt = *(const float4*)(xp + (size_t)(tk + 1) * DM);
      bf16x4 xb;
      xb[0] = (short)f2bf(xv.x); xb[1] = (short)f2bf(xv.y);
      xb[2] = (short)f2bf(xv.z); xb[3] = (short)f2bf(xv.w);
      *(bf16x4*)(Xb + (size_t)(t0 + tk) * DM + dd) = xb;
      float a[NE] = {};
      const float* xs = (const float*)&xv;
      #pragma unroll
      for (int j = 0; j < 4; ++j) {
        const float xj = xs[j];
        const float* wr = (const float*)&wgr[j][0];
        #pragma unroll
        for (int e = 0; e < NE; ++e) a[e] += xj * wr[e];
      }
      float t0v[4];
      #pragma unroll
      for (int j = 0; j < 4; ++j) {
        float send = (lane & 1) ? a[j] : a[j + 4];
        float keep = (lane & 1) ? a[j + 4] : a[j];
        t0v[j] = keep + __shfl_xor(send, 1);
      }
      float t1v[2];
      #pragma unroll
      for (int j = 0; j < 2; ++j) {
        float send = (lane & 2) ? t0v[j] : t0v[j + 2];
        float keep = (lane & 2) ? t0v[j + 2] : t0v[j];
        t1v[j] = keep + __shfl_xor(send, 2);
      }
      {
        float send = (lane & 4) ? t1v[0] : t1v[1];
        float keep = (lane & 4) ? t1v[1] : t1v[0];
        float t2 = keep + __shfl_xor(send, 4);
        t2 += __shfl_xor(t2, 8);
        t2 += __shfl_xor(t2, 16);
        t2 += __shfl_xor(t2, 32);
        if (lane < NE) part[w][tk][ebit] = t2;
      }
      xv = nxt;
    }
    __syncthreads();
    const int tid = threadIdx.x;
    if (tid < PW) {
      float lg[NE];
      #pragma unroll
      for (int e = 0; e < NE; ++e)
        lg[e] = part[0][tid][e] + part[1][tid][e] + part[2][tid][e] + part[3][tid][e];
      int e0 = 0; float l0 = lg[0];
      #pragma unroll
      for (int e = 1; e < NE; ++e) if (lg[e] > l0) { l0 = lg[e]; e0 = e; }
      int e1 = -1; float l1 = -3.4e38f;
      #pragma unroll
      for (int e = 0; e < NE; ++e) if (e != e0 && lg[e] > l1) { l1 = lg[e]; e1 = e; }
      const float p1  = __expf(l1 - l0);
      const float inv = 1.f / (1.f + p1);
      const float g0 = 0.5f * inv, g1 = 0.5f * p1 * inv;   // ADAPTER_SCALE folded
      float g[NE];
      #pragma unroll
      for (int e = 0; e < NE; ++e) g[e] = (e == e0) ? g0 : ((e == e1) ? g1 : 0.f);
      *(float4*)(sg + (size_t)(t0 + tid) * NE)     = *(float4*)&g[0];
      *(float4*)(sg + (size_t)(t0 + tid) * NE + 4) = *(float4*)&g[4];
      const int es0 = min(e0, e1), es1 = max(e0, e1);
      route[t0 + tid] = es0 | (es1 << 4);
    }
  } else {
    const int rr = threadIdx.x >> 2;
    const int cc = (threadIdx.x & 3) * 16;
    const int bx = blockIdx.x - NPREP;
    if (bx < 128) {
      const int e  = bx >> 4;
      const int d0 = (bx & 15) * 64;
      const float* src = Wd + ((size_t)e * DM + d0 + rr) * BOT + cc;
      #pragma unroll
      for (int i = 0; i < 4; ++i) {
        float4 v = *(const float4*)(src + i * 4);
        tl[rr][cc + i * 4 + 0] = f2bf(v.x);
        tl[rr][cc + i * 4 + 1] = f2bf(v.y);
        tl[rr][cc + i * 4 + 2] = f2bf(v.z);
        tl[rr][cc + i * 4 + 3] = f2bf(v.w);
      }
      __syncthreads();
      bf16x8 o0, o1;
      #pragma unroll
      for (int k = 0; k < 8; ++k) o0[k] = (short)tl[cc + k][rr];
      #pragma unroll
      for (int k = 0; k < 8; ++k) o1[k] = (short)tl[cc + 8 + k][rr];
      ushort* dst = WdT + ((size_t)e * BOT + rr) * DM + d0 + cc;
      *(bf16x8*)dst       = o0;
      *(bf16x8*)(dst + 8) = o1;
    } else {
      const int b2 = bx - 128;                 // 0..127: WuT[d][n], ld 512
      const int n0 = (b2 >> 4) * 64;
      const int d0 = (b2 & 15) * 64;
      const float* src = Wu + (size_t)(n0 + rr) * DM + d0 + cc;
      #pragma unroll
      for (int i = 0; i < 4; ++i) {
        float4 v = *(const float4*)(src + i * 4);
        tl[rr][cc + i * 4 + 0] = f2bf(v.x);
        tl[rr][cc + i * 4 + 1] = f2bf(v.y);
        tl[rr][cc + i * 4 + 2] = f2bf(v.z);
        tl[rr][cc + i * 4 + 3] = f2bf(v.w);
      }
      __syncthreads();
      bf16x8 o0, o1;
      #pragma unroll
      for (int k = 0; k < 8; ++k) o0[k] = (short)tl[cc + k][rr];
      #pragma unroll
      for (int k = 0; k < 8; ++k) o1[k] = (short)tl[cc + 8 + k][rr];
      ushort* dst = WuT + (size_t)(d0 + rr) * HD + n0 + cc;
      *(bf16x8*)dst       = o0;
      *(bf16x8*)(dst + 8) = o1;
    }
  }
}

// ---- route: wave-ballot compaction into expert lists + pair lists ----------
// grid 32 x 256 (= 128 waves x 64 tokens). One atomic per expert/pair per wave.
__global__ __launch_bounds__(256)
void route_kernel(const int* __restrict__ route, const float* __restrict__ sg,
                  int* __restrict__ cnt, int* __restrict__ idx1,
                  float* __restrict__ scl1, int* __restrict__ plist) {
  int* pcnt = cnt + 8;
  const int lane = threadIdx.x & 63;
  const int w    = threadIdx.x >> 6;
  const int t    = (blockIdx.x * 4 + w) * 64 + lane;
  const int r    = route[t];
  const int es0 = r & 15, es1 = (r >> 4) & 15;
  const float g0 = sg[(size_t)t * NE + es0];
  const float g1 = sg[(size_t)t * NE + es1];
  const int p = es0 * 7 - ((es0 * (es0 - 1)) >> 1) + (es1 - es0 - 1);
  const unsigned long long lower = (1ull << lane) - 1ull;
  #pragma unroll
  for (int e = 0; e < NE; ++e) {
    unsigned long long m0 = __ballot(es0 == e);
    unsigned long long m1 = __ballot(es1 == e);
    unsigned long long mm = m0 | m1;
    if (mm) {
      const int c0 = __popcll(m0);
      const int c  = c0 + __popcll(m1);
      const int ldr = __ffsll((long long)mm) - 1;
      int b = 0;
      if (lane == ldr) b = atomicAdd(&cnt[e], c);
      b = __shfl(b, ldr);
      if (es0 == e) {
        const int rk = __popcll(m0 & lower);
        idx1[e * T_TOK + b + rk] = (t << 1);
        scl1[e * T_TOK + b + rk] = g0;
      }
      if (es1 == e) {
        const int rk = c0 + __popcll(m1 & lower);
        idx1[e * T_TOK + b + rk] = (t << 1) | 1;
        scl1[e * T_TOK + b + rk] = g1;
      }
    }
  }
  #pragma unroll
  for (int pp = 0; pp < 28; ++pp) {
    unsigned long long m = __ballot(p == pp);
    if (m) {
      const int c = __popcll(m);
      const int ldr = __ffsll((long long)m) - 1;
      int b = 0;
      if (lane == ldr) b = atomicAdd(&pcnt[pp], c);
      b = __shfl(b, ldr);
      if (p == pp) plist[pp * T_TOK + b + __popcll(m & lower)] = t;
    }
  }
}

// ---- sparse stage 1: Hc[tok][slot*64+b] = relu(x_tok @ Wd_e + bd_e) * gate --
// grid 136 (Σ_e ceil(cnt_e/128)); 128 gathered rows x 64 cols, K=1024.
__global__ __launch_bounds__(256)
void gemm1s(const ushort* __restrict__ Xb, const ushort* __restrict__ WdT,
            const int* __restrict__ cnt, const int* __restrict__ idx1,
            const float* __restrict__ scl1, const float* __restrict__ bd,
            ushort* __restrict__ Hc) {
  __shared__ __attribute__((aligned(16))) ushort sA[3][128 * 64];
  __shared__ __attribute__((aligned(16))) ushort sB[3][64 * 64];
  int e = -1, seg = 0, at = 0;
  #pragma unroll
  for (int ee = 0; ee < NE; ++ee) {
    const int nt = (cnt[ee] + 127) >> 7;
    if (e < 0 && (int)blockIdx.x < at + nt) { e = ee; seg = blockIdx.x - at; }
    at += nt;
  }
  if (e < 0) return;
  const int ne    = cnt[e];
  const int rbase = seg * 128;
  const int lbase = e * T_TOK + rbase;
  const int nval  = min(128, ne - rbase);
  const int lane = threadIdx.x & 63;
  const int w    = threadIdx.x >> 6;
  const int wm = (w >> 1) * 64;
  const int wn = (w & 1) * 32;
  const int sr = lane >> 3;
  const int sc = ((lane & 7) * 8) ^ (sr << 3);
  const int lr = lane & 15;
  const int kg = lane >> 4;
  const int swz = (lr & 7) << 3;
  int atok[4];
  #pragma unroll
  for (int c = 0; c < 4; ++c) {
    const int rr = w * 32 + c * 8 + sr;
    atok[c] = idx1[lbase + (rr < nval ? rr : 0)] >> 1;
  }
  f32x4 acc[4][2] = {};

#define STAGE1(buf, kt) do {                                                      \
    const int k0_ = (kt) << 6;                                                    \
    _Pragma("unroll")                                                             \
    for (int c = 0; c < 4; ++c) {                                                 \
      const ushort* ga = Xb + (size_t)atok[c] * DM + k0_ + sc;                    \
      __builtin_amdgcn_global_load_lds((const __attribute__((address_space(1))) void*)ga, \
          (__attribute__((address_space(3))) void*)&sA[buf][(w * 32 + c * 8) * 64], 16, 0, 0); \
    }                                                                             \
    _Pragma("unroll")                                                             \
    for (int c = 0; c < 2; ++c) {                                                 \
      const ushort* gb = WdT + (size_t)(e * 64 + w * 16 + c * 8 + sr) * DM + k0_ + sc; \
      __builtin_amdgcn_global_load_lds((const __attribute__((address_space(1))) void*)gb, \
          (__attribute__((address_space(3))) void*)&sB[buf][(w * 16 + c * 8) * 64], 16, 0, 0); \
    } } while (0)

  STAGE1(0, 0);
  STAGE1(1, 1);
  for (int kt = 0; kt < 16; ++kt) {
    const int cur = kt % 3;
    if (kt + 1 < 16) asm volatile("s_waitcnt vmcnt(6)" ::: "memory");
    else             asm volatile("s_waitcnt vmcnt(0)" ::: "memory");
    __builtin_amdgcn_s_barrier();
    asm volatile("" ::: "memory");
    #pragma unroll
    for (int s = 0; s < 2; ++s) {
      bf16x8 af[4], bfr[2];
      #pragma unroll
      for (int i = 0; i < 4; ++i)
        af[i] = *(const bf16x8*)&sA[cur][(wm + i * 16 + lr) * 64 + ((s * 32 + kg * 8) ^ swz)];
      #pragma unroll
      for (int j = 0; j < 2; ++j)
        bfr[j] = *(const bf16x8*)&sB[cur][(wn + j * 16 + lr) * 64 + ((s * 32 + kg * 8) ^ swz)];
      __builtin_amdgcn_s_setprio(1);
      #pragma unroll
      for (int i = 0; i < 4; ++i)
        #pragma unroll
        for (int j = 0; j < 2; ++j)
          acc[i][j] = __builtin_amdgcn_mfma_f32_16x16x32_bf16(af[i], bfr[j], acc[i][j], 0, 0, 0);
      __builtin_amdgcn_s_setprio(0);
    }
    asm volatile("" ::: "memory");
    if (kt + 2 < 16) STAGE1((kt + 2) % 3, kt + 2);
  }
#undef STAGE1

  float bdv[2];
  #pragma unroll
  for (int j = 0; j < 2; ++j) bdv[j] = bd[e * BOT + wn + j * 16 + lr];
  #pragma unroll
  for (int i = 0; i < 4; ++i) {
    #pragma unroll
    for (int r = 0; r < 4; ++r) {
      const int rl = wm + i * 16 + kg * 4 + r;
      if (rl < nval) {
        const int en  = idx1[lbase + rl];
        const float s = scl1[lbase + rl];
        ushort* hp = Hc + (size_t)(en >> 1) * 128 + (en & 1) * 64;
        #pragma unroll
        for (int j = 0; j < 2; ++j) {
          const float v = fmaxf(acc[i][j][r] + bdv[j], 0.f) * s;
          hp[wn + j * 16 + lr] = f2bf(v);
        }
      }
    }
  }
}

// ---- sparse stage 2: out[tok][d] = Hc[tok][:] @ [Wu_e0;Wu_e1][:,d] + bias ---
// grid 92*16; pair-grouped tokens (one writer per out row), K=128 (2 steps).
__global__ __launch_bounds__(256)
void gemm2s(const ushort* __restrict__ Hc, const ushort* __restrict__ WuT,
            const int* __restrict__ cnt, const int* __restrict__ plist,
            const float* __restrict__ sg, const float* __restrict__ bu,
            float* __restrict__ out, int nwg) {
  __shared__ __attribute__((aligned(16))) ushort sA[2][128 * 64];
  __shared__ __attribute__((aligned(16))) ushort sB[2][64 * 64];
  const int* pcnt = cnt + 8;
  const int lb = (blockIdx.x % 8) * (nwg / 8) + blockIdx.x / 8;  // XCD-chunked
  const int mt = lb >> 4;
  const int tile_n = (lb & 15) * 64;
  int p = -1, seg = 0, at = 0;
  #pragma unroll
  for (int pp = 0; pp < 28; ++pp) {
    const int nt = (pcnt[pp] + 127) >> 7;
    if (p < 0 && mt < at + nt) { p = pp; seg = mt - at; }
    at += nt;
  }
  if (p < 0) return;
  int es0 = 0, es1 = 1, a2 = 0;
  #pragma unroll
  for (int a = 0; a < NE; ++a) {
    const int ca = 7 - a;
    if (p >= a2 && p < a2 + ca) { es0 = a; es1 = a + 1 + (p - a2); }
    a2 += ca;
  }
  const int np    = pcnt[p];
  const int rbase = seg * 128;
  const int lbase = p * T_TOK + rbase;
  const int nval  = min(128, np - rbase);
  const int lane = threadIdx.x & 63;
  const int w    = threadIdx.x >> 6;
  const int wm = (w >> 1) * 64;
  const int wn = (w & 1) * 32;
  const int sr = lane >> 3;
  const int sc = ((lane & 7) * 8) ^ (sr << 3);
  const int lr = lane & 15;
  const int kg = lane >> 4;
  const int swz = (lr & 7) << 3;
  int atok[4];
  #pragma unroll
  for (int c = 0; c < 4; ++c) {
    const int rr = w * 32 + c * 8 + sr;
    atok[c] = plist[lbase + (rr < nval ? rr : 0)];
  }
  const int bc0 = es0 * 64, bc1 = es1 * 64;
  f32x4 acc[4][2] = {};

#define STAGE2(buf, kt, bc) do {                                                  \
    _Pragma("unroll")                                                             \
    for (int c = 0; c < 4; ++c) {                                                 \
      const ushort* ga = Hc + (size_t)atok[c] * 128 + (kt) * 64 + sc;             \
      __builtin_amdgcn_global_load_lds((const __attribute__((address_space(1))) void*)ga, \
          (__attribute__((address_space(3))) void*)&sA[buf][(w * 32 + c * 8) * 64], 16, 0, 0); \
    }                                                                             \
    _Pragma("unroll")                                                             \
    for (int c = 0; c < 2; ++c) {                                                 \
      const ushort* gb = WuT + (size_t)(tile_n + w * 16 + c * 8 + sr) * HD + (bc) + sc; \
      __builtin_amdgcn_global_load_lds((const __attribute__((address_space(1))) void*)gb, \
          (__attribute__((address_space(3))) void*)&sB[buf][(w * 16 + c * 8) * 64], 16, 0, 0); \
    } } while (0)

#define COMPUTE2(cur) do {                                                        \
    _Pragma("unroll")                                                             \
    for (int s = 0; s < 2; ++s) {                                                 \
      bf16x8 af[4], bfr[2];                                                       \
      _Pragma("unroll")                                                           \
      for (int i = 0; i < 4; ++i)                                                 \
        af[i] = *(const bf16x8*)&sA[cur][(wm + i * 16 + lr) * 64 + ((s * 32 + kg * 8) ^ swz)]; \
      _Pragma("unroll")                                                           \
      for (int j = 0; j < 2; ++j)                                                 \
        bfr[j] = *(const bf16x8*)&sB[cur][(wn + j * 16 + lr) * 64 + ((s * 32 + kg * 8) ^ swz)]; \
      __builtin_amdgcn_s_setprio(1);                                              \
      _Pragma("unroll")                                                           \
      for (int i = 0; i < 4; ++i)                                                 \
        _Pragma("unroll")                                                         \
        for (int j = 0; j < 2; ++j)                                               \
          acc[i][j] = __builtin_amdgcn_mfma_f32_16x16x32_bf16(af[i], bfr[j], acc[i][j], 0, 0, 0); \
      __builtin_amdgcn_s_setprio(0);                                              \
    } } while (0)

  STAGE2(0, 0, bc0);
  STAGE2(1, 1, bc1);
  asm volatile("s_waitcnt vmcnt(6)" ::: "memory");
  __builtin_amdgcn_s_barrier();
  asm volatile("" ::: "memory");
  COMPUTE2(0);
  asm volatile("s_waitcnt vmcnt(0)" ::: "memory");
  __builtin_amdgcn_s_barrier();
  asm volatile("" ::: "memory");
  COMPUTE2(1);
#undef STAGE2
#undef COMPUTE2

  float bu0[2], bu1[2];
  #pragma unroll
  for (int j = 0; j < 2; ++j) {
    const int col = tile_n + wn + j * 16 + lr;
    bu0[j] = bu[(size_t)es0 * DM + col];
    bu1[j] = bu[(size_t)es1 * DM + col];
  }
  #pragma unroll
  for (int i = 0; i < 4; ++i) {
    #pragma unroll
    for (int r = 0; r < 4; ++r) {
      const int rl = wm + i * 16 + kg * 4 + r;
      if (rl < nval) {
        const int tok = plist[lbase + rl];
        const float g0 = sg[(size_t)tok * NE + es0];
        const float g1 = sg[(size_t)tok * NE + es1];
        #pragma unroll
        for (int j = 0; j < 2; ++j) {
          const int col = tile_n + wn + j * 16 + lr;
          out[(size_t)tok * DM + col] = acc[i][j][r] + g0 * bu0[j] + g1 * bu1[j];
        }
      }
    }
  }
}

extern "C" void kernel_launch(void* const* d_in, const int* in_sizes, int n_in,
                              void* d_out, int out_size, void* d_ws, size_t ws_size,
                              hipStream_t stream) {
  const float* x  = (const float*)d_in[0];
  const float* wg = (const float*)d_in[1];
  // d_in[2] = w_noise: unused (reference gates on clean logits)
  const float* Wd = (const float*)d_in[3];
  const float* bd = (const float*)d_in[4];
  const float* Wu = (const float*)d_in[5];
  const float* bu = (const float*)d_in[6];
  float* out = (float*)d_out;

  char* ws = (char*)d_ws;
  ushort* Xb    = (ushort*)(ws + XB_OFF);
  ushort* Hc    = (ushort*)(ws + HC_OFF);
  ushort* WdT   = (ushort*)(ws + WDT_OFF);
  ushort* WuT   = (ushort*)(ws + WUT_OFF);
  float*  sgw   = (float*) (ws + SG_OFF);
  int*    route = (int*)   (ws + RT_OFF);
  int*    idx1  = (int*)   (ws + IDX_OFF);
  float*  scl1  = (float*) (ws + SCL_OFF);
  int*    plist = (int*)   (ws + PL_OFF);
  int*    cnt   = (int*)   (ws + CNT_OFF);

  prep_cvt_kernel<<<dim3(NPREP + 256), dim3(256), 0, stream>>>(
      x, wg, Wd, Wu, Xb, sgw, route, WdT, WuT, cnt);
  route_kernel<<<dim3(32), dim3(256), 0, stream>>>(
      route, sgw, cnt, idx1, scl1, plist);
  gemm1s<<<dim3(136), dim3(256), 0, stream>>>(
      Xb, WdT, cnt, idx1, scl1, bd, Hc);
  gemm2s<<<dim3(1472), dim3(256), 0, stream>>>(
      Hc, WuT, cnt, plist, sgw, bu, out, 1472);
}

// Round 9
// 70.957 us; speedup vs baseline: 1.4737x; 1.4737x over previous
//
#include <hip/hip_runtime.h>
#include <stdint.h>

#define T_TOK 8192
#define DM    1024
#define NE    8
#define BOT   64
#define HD    512
#define PW    8
#define NPREP (T_TOK / PW)

// workspace offsets (bytes)
#define XB_OFF   0u
#define HC_OFF   16777216u   // Hc: 8192 x 128 bf16 = 2 MB
#define WDT_OFF  18874368u   // WdT: 512 x 1024 bf16 = 1 MB
#define WUT_OFF  19922944u   // WuT: 1024 x 512 bf16 = 1 MB
#define SG_OFF   20971520u   // sg: 8192 x 8 f32 = 256 KB
#define RT_OFF   21233664u   // route: 8192 int = 32 KB
#define PL_OFF   21266432u   // plist: 28 x 8192 int = 896 KB
#define CNT_OFF  22708224u   // cnt[8]+pcnt[28]

typedef __attribute__((ext_vector_type(8))) short bf16x8;
typedef __attribute__((ext_vector_type(4))) short bf16x4;
typedef __attribute__((ext_vector_type(4))) float f32x4;

__device__ __forceinline__ ushort f2bf(float f) {
  union { float f; uint32_t u; } v; v.f = f;
  uint32_t r = (v.u + 0x7fffu + ((v.u >> 16) & 1u)) >> 16;
  return (ushort)r;
}

// ---- prep (blocks 0..1023): X->bf16, fp32 gating, top-2, route word --------
// ---- cvt  (blocks 1024..1279): WdT / WuT transposes ------------------------
__global__ __launch_bounds__(256, 2)
void prep_cvt_kernel(const float* __restrict__ x, const float* __restrict__ wg,
                     const float* __restrict__ Wd, const float* __restrict__ Wu,
                     ushort* __restrict__ Xb, float* __restrict__ sg,
                     int* __restrict__ route, ushort* __restrict__ WdT,
                     ushort* __restrict__ WuT, int* __restrict__ cntz) {
  __shared__ float part[4][PW][NE];
  __shared__ ushort tl[64][72];
  if (blockIdx.x < NPREP) {
    if (blockIdx.x == 0 && threadIdx.x < 36) cntz[threadIdx.x] = 0;
    const int lane = threadIdx.x & 63;
    const int w    = threadIdx.x >> 6;
    const int t0   = blockIdx.x * PW;
    const int dd   = w * 256 + lane * 4;
    float4 wgr[4][2];
    #pragma unroll
    for (int j = 0; j < 4; ++j) {
      wgr[j][0] = *(const float4*)(wg + (size_t)(dd + j) * NE);
      wgr[j][1] = *(const float4*)(wg + (size_t)(dd + j) * NE + 4);
    }
    const int ebit = ((lane & 1) << 2) | (lane & 2) | ((lane >> 2) & 1);
    const float* xp = x + (size_t)t0 * DM + dd;
    float4 xv = *(const float4*)xp;
    #pragma unroll
    for (int tk = 0; tk < PW; ++tk) {
      float4 nxt = {};
      if (tk + 1 < PW) nxt = *(const float4*)(xp + (size_t)(tk + 1) * DM);
      bf16x4 xb;
      xb[0] = (short)f2bf(xv.x); xb[1] = (short)f2bf(xv.y);
      xb[2] = (short)f2bf(xv.z); xb[3] = (short)f2bf(xv.w);
      *(bf16x4*)(Xb + (size_t)(t0 + tk) * DM + dd) = xb;
      float a[NE] = {};
      const float* xs = (const float*)&xv;
      #pragma unroll
      for (int j = 0; j < 4; ++j) {
        const float xj = xs[j];
        const float* wr = (const float*)&wgr[j][0];
        #pragma unroll
        for (int e = 0; e < NE; ++e) a[e] += xj * wr[e];
      }
      float t0v[4];
      #pragma unroll
      for (int j = 0; j < 4; ++j) {
        float send = (lane & 1) ? a[j] : a[j + 4];
        float keep = (lane & 1) ? a[j + 4] : a[j];
        t0v[j] = keep + __shfl_xor(send, 1);
      }
      float t1v[2];
      #pragma unroll
      for (int j = 0; j < 2; ++j) {
        float send = (lane & 2) ? t0v[j] : t0v[j + 2];
        float keep = (lane & 2) ? t0v[j + 2] : t0v[j];
        t1v[j] = keep + __shfl_xor(send, 2);
      }
      {
        float send = (lane & 4) ? t1v[0] : t1v[1];
        float keep = (lane & 4) ? t1v[1] : t1v[0];
        float t2 = keep + __shfl_xor(send, 4);
        t2 += __shfl_xor(t2, 8);
        t2 += __shfl_xor(t2, 16);
        t2 += __shfl_xor(t2, 32);
        if (lane < NE) part[w][tk][ebit] = t2;
      }
      xv = nxt;
    }
    __syncthreads();
    const int tid = threadIdx.x;
    if (tid < PW) {
      float lg[NE];
      #pragma unroll
      for (int e = 0; e < NE; ++e)
        lg[e] = part[0][tid][e] + part[1][tid][e] + part[2][tid][e] + part[3][tid][e];
      int e0 = 0; float l0 = lg[0];
      #pragma unroll
      for (int e = 1; e < NE; ++e) if (lg[e] > l0) { l0 = lg[e]; e0 = e; }
      int e1 = -1; float l1 = -3.4e38f;
      #pragma unroll
      for (int e = 0; e < NE; ++e) if (e != e0 && lg[e] > l1) { l1 = lg[e]; e1 = e; }
      const float p1  = __expf(l1 - l0);
      const float inv = 1.f / (1.f + p1);
      const float g0 = 0.5f * inv, g1 = 0.5f * p1 * inv;   // ADAPTER_SCALE folded
      float g[NE];
      #pragma unroll
      for (int e = 0; e < NE; ++e) g[e] = (e == e0) ? g0 : ((e == e1) ? g1 : 0.f);
      *(float4*)(sg + (size_t)(t0 + tid) * NE)     = *(float4*)&g[0];
      *(float4*)(sg + (size_t)(t0 + tid) * NE + 4) = *(float4*)&g[4];
      const int es0 = min(e0, e1), es1 = max(e0, e1);
      route[t0 + tid] = es0 | (es1 << 4);
    }
  } else {
    const int rr = threadIdx.x >> 2;
    const int cc = (threadIdx.x & 3) * 16;
    const int bx = blockIdx.x - NPREP;
    if (bx < 128) {
      const int e  = bx >> 4;
      const int d0 = (bx & 15) * 64;
      const float* src = Wd + ((size_t)e * DM + d0 + rr) * BOT + cc;
      #pragma unroll
      for (int i = 0; i < 4; ++i) {
        float4 v = *(const float4*)(src + i * 4);
        tl[rr][cc + i * 4 + 0] = f2bf(v.x);
        tl[rr][cc + i * 4 + 1] = f2bf(v.y);
        tl[rr][cc + i * 4 + 2] = f2bf(v.z);
        tl[rr][cc + i * 4 + 3] = f2bf(v.w);
      }
      __syncthreads();
      bf16x8 o0, o1;
      #pragma unroll
      for (int k = 0; k < 8; ++k) o0[k] = (short)tl[cc + k][rr];
      #pragma unroll
      for (int k = 0; k < 8; ++k) o1[k] = (short)tl[cc + 8 + k][rr];
      ushort* dst = WdT + ((size_t)e * BOT + rr) * DM + d0 + cc;
      *(bf16x8*)dst       = o0;
      *(bf16x8*)(dst + 8) = o1;
    } else {
      const int b2 = bx - 128;                 // WuT[d][n], ld 512
      const int n0 = (b2 >> 4) * 64;
      const int d0 = (b2 & 15) * 64;
      const float* src = Wu + (size_t)(n0 + rr) * DM + d0 + cc;
      #pragma unroll
      for (int i = 0; i < 4; ++i) {
        float4 v = *(const float4*)(src + i * 4);
        tl[rr][cc + i * 4 + 0] = f2bf(v.x);
        tl[rr][cc + i * 4 + 1] = f2bf(v.y);
        tl[rr][cc + i * 4 + 2] = f2bf(v.z);
        tl[rr][cc + i * 4 + 3] = f2bf(v.w);
      }
      __syncthreads();
      bf16x8 o0, o1;
      #pragma unroll
      for (int k = 0; k < 8; ++k) o0[k] = (short)tl[cc + k][rr];
      #pragma unroll
      for (int k = 0; k < 8; ++k) o1[k] = (short)tl[cc + 8 + k][rr];
      ushort* dst = WuT + (size_t)(d0 + rr) * HD + n0 + cc;
      *(bf16x8*)dst       = o0;
      *(bf16x8*)(dst + 8) = o1;
    }
  }
}

// ---- route v2: LDS histogram + 28 PARALLEL global atomics + scatter --------
// One LDS atomic (rank) + one global atomic (28 threads concurrently) on the
// critical path -- replaces round-8's 36 serially-dependent global rounds.
__global__ __launch_bounds__(256)
void route_kernel(const int* __restrict__ route, int* __restrict__ cnt,
                  int* __restrict__ plist) {
  __shared__ int hist[28];
  __shared__ int base[28];
  int* pcnt = cnt + 8;
  const int tid = threadIdx.x;
  if (tid < 28) hist[tid] = 0;
  __syncthreads();
  const int t = blockIdx.x * 256 + tid;
  const int r = route[t];
  const int es0 = r & 15, es1 = (r >> 4) & 15;
  const int p = es0 * 7 - ((es0 * (es0 - 1)) >> 1) + (es1 - es0 - 1);
  const int lrank = atomicAdd(&hist[p], 1);
  __syncthreads();
  if (tid < 28 && hist[tid] > 0) base[tid] = atomicAdd(&pcnt[tid], hist[tid]);
  __syncthreads();
  plist[p * T_TOK + base[p] + lrank] = t;
}

// ---- stage 1 (pair-grouped): Hc[tok][0:64]=e0-half, [64:128]=e1-half -------
// grid 92 (>= Sum ceil(np/128)); 128 gathered rows x 128 cols, K=1024.
// 3-buf, 1 barrier/K-step, counted vmcnt(8); per-lane gather via global src.
__global__ __launch_bounds__(256)
void gemm1p(const ushort* __restrict__ Xb, const ushort* __restrict__ WdT,
            const int* __restrict__ cnt, const int* __restrict__ plist,
            const float* __restrict__ sg, const float* __restrict__ bd,
            ushort* __restrict__ Hc) {
  __shared__ __attribute__((aligned(16))) ushort sA[3][128 * 64];
  __shared__ __attribute__((aligned(16))) ushort sB[3][128 * 64];
  const int* pcnt = cnt + 8;
  int p = -1, seg = 0, at = 0;
  #pragma unroll
  for (int pp = 0; pp < 28; ++pp) {
    const int nt = (pcnt[pp] + 127) >> 7;
    if (p < 0 && (int)blockIdx.x < at + nt) { p = pp; seg = blockIdx.x - at; }
    at += nt;
  }
  if (p < 0) return;
  int es0 = 0, es1 = 1, a2 = 0;
  #pragma unroll
  for (int a = 0; a < NE; ++a) {
    const int ca = 7 - a;
    if (p >= a2 && p < a2 + ca) { es0 = a; es1 = a + 1 + (p - a2); }
    a2 += ca;
  }
  const int np    = pcnt[p];
  const int rbase = seg * 128;
  const int lbase = p * T_TOK + rbase;
  const int nval  = min(128, np - rbase);
  const int lane = threadIdx.x & 63;
  const int w    = threadIdx.x >> 6;
  const int wm = (w >> 1) * 64;
  const int wn = (w & 1) * 64;
  const int sr = lane >> 3;
  const int sc = ((lane & 7) * 8) ^ (sr << 3);
  const int lr = lane & 15;
  const int kg = lane >> 4;
  const int swz = (lr & 7) << 3;
  int atok[4], brow[4];
  #pragma unroll
  for (int c = 0; c < 4; ++c) {
    const int rr = w * 32 + c * 8 + sr;
    atok[c] = plist[lbase + (rr < nval ? rr : 0)];
    brow[c] = (rr < 64) ? (es0 * 64 + rr) : (es1 * 64 + rr - 64);
  }
  f32x4 acc[4][4] = {};

#define STAGE1(buf, kt) do {                                                      \
    const int k0_ = (kt) << 6;                                                    \
    _Pragma("unroll")                                                             \
    for (int c = 0; c < 4; ++c) {                                                 \
      const ushort* ga = Xb + (size_t)atok[c] * DM + k0_ + sc;                    \
      __builtin_amdgcn_global_load_lds((const __attribute__((address_space(1))) void*)ga, \
          (__attribute__((address_space(3))) void*)&sA[buf][(w * 32 + c * 8) * 64], 16, 0, 0); \
      const ushort* gb = WdT + (size_t)brow[c] * DM + k0_ + sc;                   \
      __builtin_amdgcn_global_load_lds((const __attribute__((address_space(1))) void*)gb, \
          (__attribute__((address_space(3))) void*)&sB[buf][(w * 32 + c * 8) * 64], 16, 0, 0); \
    } } while (0)

  STAGE1(0, 0);
  STAGE1(1, 1);
  for (int kt = 0; kt < 16; ++kt) {
    const int cur = kt % 3;
    if (kt + 1 < 16) asm volatile("s_waitcnt vmcnt(8)" ::: "memory");
    else             asm volatile("s_waitcnt vmcnt(0)" ::: "memory");
    __builtin_amdgcn_s_barrier();
    asm volatile("" ::: "memory");
    #pragma unroll
    for (int s = 0; s < 2; ++s) {
      bf16x8 af[4], bfr[4];
      #pragma unroll
      for (int i = 0; i < 4; ++i)
        af[i] = *(const bf16x8*)&sA[cur][(wm + i * 16 + lr) * 64 + ((s * 32 + kg * 8) ^ swz)];
      #pragma unroll
      for (int j = 0; j < 4; ++j)
        bfr[j] = *(const bf16x8*)&sB[cur][(wn + j * 16 + lr) * 64 + ((s * 32 + kg * 8) ^ swz)];
      __builtin_amdgcn_s_setprio(1);
      #pragma unroll
      for (int i = 0; i < 4; ++i)
        #pragma unroll
        for (int j = 0; j < 4; ++j)
          acc[i][j] = __builtin_amdgcn_mfma_f32_16x16x32_bf16(af[i], bfr[j], acc[i][j], 0, 0, 0);
      __builtin_amdgcn_s_setprio(0);
    }
    asm volatile("" ::: "memory");
    if (kt + 2 < 16) STAGE1((kt + 2) % 3, kt + 2);
  }
#undef STAGE1

  const int e = (w & 1) ? es1 : es0;         // wave's 64-col half = one expert
  float bdv[4];
  #pragma unroll
  for (int j = 0; j < 4; ++j) bdv[j] = bd[e * BOT + j * 16 + lr];
  #pragma unroll
  for (int i = 0; i < 4; ++i) {
    #pragma unroll
    for (int r = 0; r < 4; ++r) {
      const int rl = wm + i * 16 + kg * 4 + r;
      if (rl < nval) {
        const int tok = plist[lbase + rl];
        const float g = sg[(size_t)tok * NE + e];
        ushort* hp = Hc + (size_t)tok * 128 + wn;
        #pragma unroll
        for (int j = 0; j < 4; ++j)
          hp[j * 16 + lr] = f2bf(fmaxf(acc[i][j][r] + bdv[j], 0.f) * g);
      }
    }
  }
}

// ---- stage 2 (pair-grouped): out[tok][d] = Hc[tok][:] @ [Wu_e0;Wu_e1] + bias
// grid 92*8; 128 gathered rows x 128 cols, K=128 (2 staged halves).
__global__ __launch_bounds__(256)
void gemm2p(const ushort* __restrict__ Hc, const ushort* __restrict__ WuT,
            const int* __restrict__ cnt, const int* __restrict__ plist,
            const float* __restrict__ sg, const float* __restrict__ bu,
            float* __restrict__ out, int nwg) {
  __shared__ __attribute__((aligned(16))) ushort sA[2][128 * 64];
  __shared__ __attribute__((aligned(16))) ushort sB[2][128 * 64];
  const int* pcnt = cnt + 8;
  const int lb = (blockIdx.x % 8) * (nwg / 8) + blockIdx.x / 8;  // XCD-chunked
  const int mt = lb >> 3;
  const int tile_n = (lb & 7) * 128;
  int p = -1, seg = 0, at = 0;
  #pragma unroll
  for (int pp = 0; pp < 28; ++pp) {
    const int nt = (pcnt[pp] + 127) >> 7;
    if (p < 0 && mt < at + nt) { p = pp; seg = mt - at; }
    at += nt;
  }
  if (p < 0) return;
  int es0 = 0, es1 = 1, a2 = 0;
  #pragma unroll
  for (int a = 0; a < NE; ++a) {
    const int ca = 7 - a;
    if (p >= a2 && p < a2 + ca) { es0 = a; es1 = a + 1 + (p - a2); }
    a2 += ca;
  }
  const int np    = pcnt[p];
  const int rbase = seg * 128;
  const int lbase = p * T_TOK + rbase;
  const int nval  = min(128, np - rbase);
  const int lane = threadIdx.x & 63;
  const int w    = threadIdx.x >> 6;
  const int wm = (w >> 1) * 64;
  const int wn = (w & 1) * 64;
  const int sr = lane >> 3;
  const int sc = ((lane & 7) * 8) ^ (sr << 3);
  const int lr = lane & 15;
  const int kg = lane >> 4;
  const int swz = (lr & 7) << 3;
  int atok[4];
  #pragma unroll
  for (int c = 0; c < 4; ++c) {
    const int rr = w * 32 + c * 8 + sr;
    atok[c] = plist[lbase + (rr < nval ? rr : 0)];
  }
  const int bc0 = es0 * 64, bc1 = es1 * 64;
  f32x4 acc[4][4] = {};

#define STAGE2(buf, kt, bc) do {                                                  \
    _Pragma("unroll")                                                             \
    for (int c = 0; c < 4; ++c) {                                                 \
      const ushort* ga = Hc + (size_t)atok[c] * 128 + (kt) * 64 + sc;             \
      __builtin_amdgcn_global_load_lds((const __attribute__((address_space(1))) void*)ga, \
          (__attribute__((address_space(3))) void*)&sA[buf][(w * 32 + c * 8) * 64], 16, 0, 0); \
      const ushort* gb = WuT + (size_t)(tile_n + w * 32 + c * 8 + sr) * HD + (bc) + sc; \
      __builtin_amdgcn_global_load_lds((const __attribute__((address_space(1))) void*)gb, \
          (__attribute__((address_space(3))) void*)&sB[buf][(w * 32 + c * 8) * 64], 16, 0, 0); \
    } } while (0)

#define COMPUTE2(cur) do {                                                        \
    _Pragma("unroll")                                                             \
    for (int s = 0; s < 2; ++s) {                                                 \
      bf16x8 af[4], bfr[4];                                                       \
      _Pragma("unroll")                                                           \
      for (int i = 0; i < 4; ++i)                                                 \
        af[i] = *(const bf16x8*)&sA[cur][(wm + i * 16 + lr) * 64 + ((s * 32 + kg * 8) ^ swz)]; \
      _Pragma("unroll")                                                           \
      for (int j = 0; j < 4; ++j)                                                 \
        bfr[j] = *(const bf16x8*)&sB[cur][(wn + j * 16 + lr) * 64 + ((s * 32 + kg * 8) ^ swz)]; \
      __builtin_amdgcn_s_setprio(1);                                              \
      _Pragma("unroll")                                                           \
      for (int i = 0; i < 4; ++i)                                                 \
        _Pragma("unroll")                                                         \
        for (int j = 0; j < 4; ++j)                                               \
          acc[i][j] = __builtin_amdgcn_mfma_f32_16x16x32_bf16(af[i], bfr[j], acc[i][j], 0, 0, 0); \
      __builtin_amdgcn_s_setprio(0);                                              \
    } } while (0)

  STAGE2(0, 0, bc0);
  STAGE2(1, 1, bc1);
  asm volatile("s_waitcnt vmcnt(8)" ::: "memory");
  __builtin_amdgcn_s_barrier();
  asm volatile("" ::: "memory");
  COMPUTE2(0);
  asm volatile("s_waitcnt vmcnt(0)" ::: "memory");
  __builtin_amdgcn_s_barrier();
  asm volatile("" ::: "memory");
  COMPUTE2(1);
#undef STAGE2
#undef COMPUTE2

  float bu0[4], bu1[4];
  #pragma unroll
  for (int j = 0; j < 4; ++j) {
    const int col = tile_n + wn + j * 16 + lr;
    bu0[j] = bu[(size_t)es0 * DM + col];
    bu1[j] = bu[(size_t)es1 * DM + col];
  }
  #pragma unroll
  for (int i = 0; i < 4; ++i) {
    #pragma unroll
    for (int r = 0; r < 4; ++r) {
      const int rl = wm + i * 16 + kg * 4 + r;
      if (rl < nval) {
        const int tok = plist[lbase + rl];
        const float g0 = sg[(size_t)tok * NE + es0];
        const float g1 = sg[(size_t)tok * NE + es1];
        #pragma unroll
        for (int j = 0; j < 4; ++j) {
          const int col = tile_n + wn + j * 16 + lr;
          out[(size_t)tok * DM + col] = acc[i][j][r] + g0 * bu0[j] + g1 * bu1[j];
        }
      }
    }
  }
}

extern "C" void kernel_launch(void* const* d_in, const int* in_sizes, int n_in,
                              void* d_out, int out_size, void* d_ws, size_t ws_size,
                              hipStream_t stream) {
  const float* x  = (const float*)d_in[0];
  const float* wg = (const float*)d_in[1];
  // d_in[2] = w_noise: unused (reference gates on clean logits)
  const float* Wd = (const float*)d_in[3];
  const float* bd = (const float*)d_in[4];
  const float* Wu = (const float*)d_in[5];
  const float* bu = (const float*)d_in[6];
  float* out = (float*)d_out;

  char* ws = (char*)d_ws;
  ushort* Xb    = (ushort*)(ws + XB_OFF);
  ushort* Hc    = (ushort*)(ws + HC_OFF);
  ushort* WdT   = (ushort*)(ws + WDT_OFF);
  ushort* WuT   = (ushort*)(ws + WUT_OFF);
  float*  sgw   = (float*) (ws + SG_OFF);
  int*    route = (int*)   (ws + RT_OFF);
  int*    plist = (int*)   (ws + PL_OFF);
  int*    cnt   = (int*)   (ws + CNT_OFF);

  prep_cvt_kernel<<<dim3(NPREP + 256), dim3(256), 0, stream>>>(
      x, wg, Wd, Wu, Xb, sgw, route, WdT, WuT, cnt);
  route_kernel<<<dim3(32), dim3(256), 0, stream>>>(route, cnt, plist);
  gemm1p<<<dim3(92), dim3(256), 0, stream>>>(
      Xb, WdT, cnt, plist, sgw, bd, Hc);
  gemm2p<<<dim3(736), dim3(256), 0, stream>>>(
      Hc, WuT, cnt, plist, sgw, bu, out, 736);
}

// Round 11
// 55.841 us; speedup vs baseline: 1.8726x; 1.2707x over previous
//
#include <hip/hip_runtime.h>
#include <stdint.h>

#define T_TOK 8192
#define DM    1024
#define NE    8
#define BOT   64
#define HD    512
#define HD2   576   // 512 expert cols + 8 sg cols + 56 zero pad (bias folded into K)
#define PW    8     // tokens per prep block
#define NPREP (T_TOK / PW)   // 1024 prep blocks

typedef __attribute__((ext_vector_type(8))) short bf16x8;
typedef __attribute__((ext_vector_type(4))) short bf16x4;
typedef __attribute__((ext_vector_type(4))) float f32x4;

__device__ __forceinline__ ushort f2bf(float f) {
  union { float f; uint32_t u; } v; v.f = f;
  uint32_t r = (v.u + 0x7fffu + ((v.u >> 16) & 1u)) >> 16;
  return (ushort)r;
}

// ---- merged prep (blocks 0..1023) + weight transposes (1024..1295) ---------
__global__ __launch_bounds__(256, 2)
void prep_cvt_kernel(const float* __restrict__ x, const float* __restrict__ wg,
                     const float* __restrict__ Wd, const float* __restrict__ Wu,
                     const float* __restrict__ bu,
                     ushort* __restrict__ Xb, float* __restrict__ sg,
                     ushort* __restrict__ H2, ushort* __restrict__ WdT,
                     ushort* __restrict__ Wu2T) {
  __shared__ float part[4][PW][NE];
  __shared__ float sgl[PW][NE];
  __shared__ ushort tl[64][72];
  if (blockIdx.x < NPREP) {
    const int lane = threadIdx.x & 63;
    const int w    = threadIdx.x >> 6;
    const int t0   = blockIdx.x * PW;
    const int dd   = w * 256 + lane * 4;
    float4 wgr[4][2];
    #pragma unroll
    for (int j = 0; j < 4; ++j) {
      wgr[j][0] = *(const float4*)(wg + (size_t)(dd + j) * NE);
      wgr[j][1] = *(const float4*)(wg + (size_t)(dd + j) * NE + 4);
      // pin in VGPRs via SCALAR tied constraints (vector "+v" unsupported):
      // opaque defs forbid rematerialization of the wg loads per token-iter.
      asm volatile("" : "+v"(wgr[j][0].x), "+v"(wgr[j][0].y),
                        "+v"(wgr[j][0].z), "+v"(wgr[j][0].w),
                        "+v"(wgr[j][1].x), "+v"(wgr[j][1].y),
                        "+v"(wgr[j][1].z), "+v"(wgr[j][1].w));
    }
    const int ebit = ((lane & 1) << 2) | (lane & 2) | ((lane >> 2) & 1);
    const float* xp = x + (size_t)t0 * DM + dd;
    float4 xv = *(const float4*)xp;
    #pragma unroll
    for (int tk = 0; tk < PW; ++tk) {
      float4 nxt = {};
      if (tk + 1 < PW) nxt = *(const float4*)(xp + (size_t)(tk + 1) * DM);
      bf16x4 xb;
      xb[0] = (short)f2bf(xv.x); xb[1] = (short)f2bf(xv.y);
      xb[2] = (short)f2bf(xv.z); xb[3] = (short)f2bf(xv.w);
      *(bf16x4*)(Xb + (size_t)(t0 + tk) * DM + dd) = xb;
      float a[NE] = {};
      const float* xs = (const float*)&xv;
      #pragma unroll
      for (int j = 0; j < 4; ++j) {
        const float xj = xs[j];
        const float* wr = (const float*)&wgr[j][0];
        #pragma unroll
        for (int e = 0; e < NE; ++e) a[e] += xj * wr[e];
      }
      float t0v[4];
      #pragma unroll
      for (int j = 0; j < 4; ++j) {
        float send = (lane & 1) ? a[j] : a[j + 4];
        float keep = (lane & 1) ? a[j + 4] : a[j];
        t0v[j] = keep + __shfl_xor(send, 1);
      }
      float t1v[2];
      #pragma unroll
      for (int j = 0; j < 2; ++j) {
        float send = (lane & 2) ? t0v[j] : t0v[j + 2];
        float keep = (lane & 2) ? t0v[j + 2] : t0v[j];
        t1v[j] = keep + __shfl_xor(send, 2);
      }
      {
        float send = (lane & 4) ? t1v[0] : t1v[1];
        float keep = (lane & 4) ? t1v[1] : t1v[0];
        float t2 = keep + __shfl_xor(send, 4);
        t2 += __shfl_xor(t2, 8);
        t2 += __shfl_xor(t2, 16);
        t2 += __shfl_xor(t2, 32);
        if (lane < NE) part[w][tk][ebit] = t2;
      }
      xv = nxt;
    }
    __syncthreads();
    const int tid = threadIdx.x;
    if (tid < PW) {
      float lg[NE];
      #pragma unroll
      for (int e = 0; e < NE; ++e)
        lg[e] = part[0][tid][e] + part[1][tid][e] + part[2][tid][e] + part[3][tid][e];
      int e0 = 0; float l0 = lg[0];
      #pragma unroll
      for (int e = 1; e < NE; ++e) if (lg[e] > l0) { l0 = lg[e]; e0 = e; }
      int e1 = -1; float l1 = -3.4e38f;
      #pragma unroll
      for (int e = 0; e < NE; ++e) if (e != e0 && lg[e] > l1) { l1 = lg[e]; e1 = e; }
      const float p1  = __expf(l1 - l0);
      const float inv = 1.f / (1.f + p1);
      const float g0 = 0.5f * inv, g1 = 0.5f * p1 * inv;   // ADAPTER_SCALE folded
      float g[NE];
      #pragma unroll
      for (int e = 0; e < NE; ++e) g[e] = (e == e0) ? g0 : ((e == e1) ? g1 : 0.f);
      #pragma unroll
      for (int e = 0; e < NE; ++e) sgl[tid][e] = g[e];
      *(float4*)(sg + (size_t)(t0 + tid) * NE)     = *(float4*)&g[0];
      *(float4*)(sg + (size_t)(t0 + tid) * NE + 4) = *(float4*)&g[4];
    }
    __syncthreads();
    if (tid < PW * 8) {
      const int tk = tid >> 3, ch = tid & 7;
      bf16x8 v;
      #pragma unroll
      for (int k = 0; k < 8; ++k)
        v[k] = (ch == 0) ? (short)f2bf(sgl[tk][k]) : (short)0;
      *(bf16x8*)(H2 + (size_t)(t0 + tk) * HD2 + HD + ch * 8) = v;
    }
  } else {
    const int rr = threadIdx.x >> 2;
    const int cc = (threadIdx.x & 3) * 16;
    const int bx = blockIdx.x - NPREP;
    if (bx < 128) {
      const int e  = bx >> 4;
      const int d0 = (bx & 15) * 64;
      const float* src = Wd + ((size_t)e * DM + d0 + rr) * BOT + cc;
      #pragma unroll
      for (int i = 0; i < 4; ++i) {
        float4 v = *(const float4*)(src + i * 4);
        tl[rr][cc + i * 4 + 0] = f2bf(v.x);
        tl[rr][cc + i * 4 + 1] = f2bf(v.y);
        tl[rr][cc + i * 4 + 2] = f2bf(v.z);
        tl[rr][cc + i * 4 + 3] = f2bf(v.w);
      }
      __syncthreads();
      bf16x8 o0, o1;
      #pragma unroll
      for (int k = 0; k < 8; ++k) o0[k] = (short)tl[cc + k][rr];
      #pragma unroll
      for (int k = 0; k < 8; ++k) o1[k] = (short)tl[cc + 8 + k][rr];
      ushort* dst = WdT + ((size_t)e * BOT + rr) * DM + d0 + cc;
      *(bf16x8*)dst       = o0;
      *(bf16x8*)(dst + 8) = o1;
    } else {
      const int b2 = bx - 128;
      const int n0 = (b2 >> 4) * 64;
      const int d0 = (b2 & 15) * 64;
      const int n  = n0 + rr;
      #pragma unroll
      for (int i = 0; i < 4; ++i) {
        float4 v;
        if (n < HD)           v = *(const float4*)(Wu + (size_t)n * DM + d0 + cc + i * 4);
        else if (n < HD + NE) v = *(const float4*)(bu + (size_t)(n - HD) * DM + d0 + cc + i * 4);
        else { v.x = 0.f; v.y = 0.f; v.z = 0.f; v.w = 0.f; }
        tl[rr][cc + i * 4 + 0] = f2bf(v.x);
        tl[rr][cc + i * 4 + 1] = f2bf(v.y);
        tl[rr][cc + i * 4 + 2] = f2bf(v.z);
        tl[rr][cc + i * 4 + 3] = f2bf(v.w);
      }
      __syncthreads();
      bf16x8 o0, o1;
      #pragma unroll
      for (int k = 0; k < 8; ++k) o0[k] = (short)tl[cc + k][rr];
      #pragma unroll
      for (int k = 0; k < 8; ++k) o1[k] = (short)tl[cc + 8 + k][rr];
      ushort* dst = Wu2T + (size_t)(d0 + rr) * HD2 + n0 + cc;
      *(bf16x8*)dst       = o0;
      *(bf16x8*)(dst + 8) = o1;
    }
  }
}

// ---- 128(M)x64(N) bf16 GEMM, C = A @ B^T, BK=32, 3-buf, 1 barrier/step ------
// LDS/buf = (128+64)x32x2B = 12KB; x3 = 36KB -> 3 blocks/CU (12 waves/CU).
// Loop: [vmcnt(3|0); barrier; compute(kt); STAGE(kt+2)] (R7 safety proof).
// BK32 swizzle: LDS(row, chunk c) = global elem-col 8*(c ^ (row&3));
//   stage src col = 8*((lane&3) ^ ((lane>>2)&3)); read col = 8*(kg ^ (lr&3)).
// EPI=0: Hout[t][col](ld 576) = bf16(relu(acc+bd[col]) * sg[t][col>>6])
// EPI=1: Cout[t][col](ld 1024) = acc   (bias folded into K via H2 tail)
template <int EPI, int NKT, int NBX>
__global__ __launch_bounds__(256, 3)
void gemm_bt(const ushort* __restrict__ A, const ushort* __restrict__ B,
             const float* __restrict__ sg, const float* __restrict__ bd,
             ushort* __restrict__ Hout, float* __restrict__ Cout, int nwg) {
  constexpr int K = NKT * 32;
  __shared__ __attribute__((aligned(16))) ushort sA[3][128 * 32];
  __shared__ __attribute__((aligned(16))) ushort sB[3][64 * 32];
  const int lane = threadIdx.x & 63;
  const int w    = threadIdx.x >> 6;
  const int lb = (blockIdx.x % 8) * (nwg / 8) + blockIdx.x / 8;  // XCD-chunked
  const int tile_m = (lb / NBX) * 128;
  const int tile_n = (lb % NBX) * 64;
  const int wm = (w >> 1) * 64;
  const int wn = (w & 1) * 32;
  const int sr2 = lane >> 2;                      // 0..15 staged row
  const int scE = ((lane & 3) ^ (sr2 & 3)) << 3;  // pre-swizzled src col (elems)
  const int lr = lane & 15;
  const int kg = lane >> 4;
  const int rcol = ((kg ^ (lr & 3)) << 3);        // read col (elems)
  f32x4 acc[4][2] = {};

#define STAGE(buf, kt) do {                                                       \
    const int k0_ = (kt) << 5;                                                    \
    _Pragma("unroll")                                                             \
    for (int c = 0; c < 2; ++c) {                                                 \
      const ushort* ga = A + (size_t)(tile_m + w * 32 + c * 16 + sr2) * K + k0_ + scE; \
      __builtin_amdgcn_global_load_lds((const __attribute__((address_space(1))) void*)ga, \
          (__attribute__((address_space(3))) void*)&sA[buf][(w * 32 + c * 16) * 32], 16, 0, 0); \
    }                                                                             \
    {                                                                             \
      const ushort* gb = B + (size_t)(tile_n + w * 16 + sr2) * K + k0_ + scE;     \
      __builtin_amdgcn_global_load_lds((const __attribute__((address_space(1))) void*)gb, \
          (__attribute__((address_space(3))) void*)&sB[buf][(w * 16) * 32], 16, 0, 0); \
    } } while (0)

  STAGE(0, 0);
  STAGE(1, 1);
  for (int kt = 0; kt < NKT; ++kt) {
    const int cur = kt % 3;
    if (kt + 1 < NKT) asm volatile("s_waitcnt vmcnt(3)" ::: "memory");
    else              asm volatile("s_waitcnt vmcnt(0)" ::: "memory");
    __builtin_amdgcn_s_barrier();
    asm volatile("" ::: "memory");
    {
      bf16x8 af[4], bfr[2];
      #pragma unroll
      for (int i = 0; i < 4; ++i)
        af[i] = *(const bf16x8*)&sA[cur][(wm + i * 16 + lr) * 32 + rcol];
      #pragma unroll
      for (int j = 0; j < 2; ++j)
        bfr[j] = *(const bf16x8*)&sB[cur][(wn + j * 16 + lr) * 32 + rcol];
      __builtin_amdgcn_s_setprio(1);
      #pragma unroll
      for (int i = 0; i < 4; ++i)
        #pragma unroll
        for (int j = 0; j < 2; ++j)
          acc[i][j] = __builtin_amdgcn_mfma_f32_16x16x32_bf16(af[i], bfr[j], acc[i][j], 0, 0, 0);
      __builtin_amdgcn_s_setprio(0);
    }
    asm volatile("" ::: "memory");
    if (kt + 2 < NKT) STAGE((kt + 2) % 3, kt + 2);
  }
#undef STAGE

  if (EPI == 0) {
    const int e = tile_n >> 6;               // 64-col tile spans one expert
    float bdv[2];
    #pragma unroll
    for (int j = 0; j < 2; ++j) bdv[j] = bd[tile_n + wn + j * 16 + lr];
    #pragma unroll
    for (int i = 0; i < 4; ++i) {
      #pragma unroll
      for (int r = 0; r < 4; ++r) {
        const int t = tile_m + wm + i * 16 + kg * 4 + r;
        const float sglv = sg[(size_t)t * NE + e];
        #pragma unroll
        for (int j = 0; j < 2; ++j) {
          float v = fmaxf(acc[i][j][r] + bdv[j], 0.f) * sglv;
          Hout[(size_t)t * HD2 + tile_n + wn + j * 16 + lr] = f2bf(v);
        }
      }
    }
  } else {
    #pragma unroll
    for (int i = 0; i < 4; ++i) {
      #pragma unroll
      for (int r = 0; r < 4; ++r) {
        const int t = tile_m + wm + i * 16 + kg * 4 + r;
        #pragma unroll
        for (int j = 0; j < 2; ++j)
          Cout[(size_t)t * DM + tile_n + wn + j * 16 + lr] = acc[i][j][r];
      }
    }
  }
}

extern "C" void kernel_launch(void* const* d_in, const int* in_sizes, int n_in,
                              void* d_out, int out_size, void* d_ws, size_t ws_size,
                              hipStream_t stream) {
  const float* x  = (const float*)d_in[0];
  const float* wg = (const float*)d_in[1];
  // d_in[2] = w_noise: unused (reference gates on clean logits)
  const float* Wd = (const float*)d_in[3];
  const float* bd = (const float*)d_in[4];
  const float* Wu = (const float*)d_in[5];
  const float* bu = (const float*)d_in[6];
  float* out = (float*)d_out;

  char* ws = (char*)d_ws;
  ushort* Xb   = (ushort*)(ws);                      // 16 MB
  ushort* H2   = (ushort*)(ws + 16777216);           // 9.44 MB
  ushort* WdT  = (ushort*)(ws + 26214400);           // 1 MB
  ushort* Wu2T = (ushort*)(ws + 27262976);           // 1.18 MB
  float*  sgw  = (float*) (ws + 28442624);           // 256 KB

  prep_cvt_kernel<<<dim3(NPREP + 272), dim3(256), 0, stream>>>(
      x, wg, Wd, Wu, bu, Xb, sgw, H2, WdT, Wu2T);

  // H2[:, :512] = sg .* relu(X @ WdT^T + bd):  M=8192 N=512 K=1024 (32 steps)
  gemm_bt<0, 32, 8><<<dim3(512), dim3(256), 0, stream>>>(
      Xb, WdT, sgw, bd, H2, nullptr, 512);
  // out = H2 @ Wu2T^T (bias folded):           M=8192 N=1024 K=576 (18 steps)
  gemm_bt<1, 18, 16><<<dim3(1024), dim3(256), 0, stream>>>(
      H2, Wu2T, sgw, nullptr, nullptr, out, 1024);
}

// Round 12
// 51.621 us; speedup vs baseline: 2.0257x; 1.0818x over previous
//
#include <hip/hip_runtime.h>
#include <stdint.h>

#define T_TOK 8192
#define DM    1024
#define NE    8
#define BOT   64
#define HD    512
#define PW    8     // tokens per prep block
#define NPREP (T_TOK / PW)   // 1024 prep blocks

typedef __attribute__((ext_vector_type(8))) short bf16x8;
typedef __attribute__((ext_vector_type(4))) short bf16x4;
typedef __attribute__((ext_vector_type(4))) float f32x4;

__device__ __forceinline__ ushort f2bf(float f) {
  union { float f; uint32_t u; } v; v.f = f;
  uint32_t r = (v.u + 0x7fffu + ((v.u >> 16) & 1u)) >> 16;
  return (ushort)r;
}

// ---- merged prep (blocks 0..1023) + weight transposes (1024..1279) ---------
__global__ __launch_bounds__(256, 2)
void prep_cvt_kernel(const float* __restrict__ x, const float* __restrict__ wg,
                     const float* __restrict__ Wd, const float* __restrict__ Wu,
                     ushort* __restrict__ Xb, float* __restrict__ sg,
                     ushort* __restrict__ WdT, ushort* __restrict__ WuT) {
  __shared__ float part[4][PW][NE];
  __shared__ ushort tl[64][72];
  if (blockIdx.x < NPREP) {
    const int lane = threadIdx.x & 63;
    const int w    = threadIdx.x >> 6;
    const int t0   = blockIdx.x * PW;
    const int dd   = w * 256 + lane * 4;
    float4 wgr[4][2];
    #pragma unroll
    for (int j = 0; j < 4; ++j) {
      wgr[j][0] = *(const float4*)(wg + (size_t)(dd + j) * NE);
      wgr[j][1] = *(const float4*)(wg + (size_t)(dd + j) * NE + 4);
      // pin in VGPRs (scalar tied constraints): forbids per-token remat re-loads
      asm volatile("" : "+v"(wgr[j][0].x), "+v"(wgr[j][0].y),
                        "+v"(wgr[j][0].z), "+v"(wgr[j][0].w),
                        "+v"(wgr[j][1].x), "+v"(wgr[j][1].y),
                        "+v"(wgr[j][1].z), "+v"(wgr[j][1].w));
    }
    const int ebit = ((lane & 1) << 2) | (lane & 2) | ((lane >> 2) & 1);
    const float* xp = x + (size_t)t0 * DM + dd;
    float4 xv = *(const float4*)xp;
    #pragma unroll
    for (int tk = 0; tk < PW; ++tk) {
      float4 nxt = {};
      if (tk + 1 < PW) nxt = *(const float4*)(xp + (size_t)(tk + 1) * DM);
      bf16x4 xb;
      xb[0] = (short)f2bf(xv.x); xb[1] = (short)f2bf(xv.y);
      xb[2] = (short)f2bf(xv.z); xb[3] = (short)f2bf(xv.w);
      *(bf16x4*)(Xb + (size_t)(t0 + tk) * DM + dd) = xb;
      float a[NE] = {};
      const float* xs = (const float*)&xv;
      #pragma unroll
      for (int j = 0; j < 4; ++j) {
        const float xj = xs[j];
        const float* wr = (const float*)&wgr[j][0];
        #pragma unroll
        for (int e = 0; e < NE; ++e) a[e] += xj * wr[e];
      }
      float t0v[4];
      #pragma unroll
      for (int j = 0; j < 4; ++j) {
        float send = (lane & 1) ? a[j] : a[j + 4];
        float keep = (lane & 1) ? a[j + 4] : a[j];
        t0v[j] = keep + __shfl_xor(send, 1);
      }
      float t1v[2];
      #pragma unroll
      for (int j = 0; j < 2; ++j) {
        float send = (lane & 2) ? t0v[j] : t0v[j + 2];
        float keep = (lane & 2) ? t0v[j + 2] : t0v[j];
        t1v[j] = keep + __shfl_xor(send, 2);
      }
      {
        float send = (lane & 4) ? t1v[0] : t1v[1];
        float keep = (lane & 4) ? t1v[1] : t1v[0];
        float t2 = keep + __shfl_xor(send, 4);
        t2 += __shfl_xor(t2, 8);
        t2 += __shfl_xor(t2, 16);
        t2 += __shfl_xor(t2, 32);
        if (lane < NE) part[w][tk][ebit] = t2;
      }
      xv = nxt;
    }
    __syncthreads();
    const int tid = threadIdx.x;
    if (tid < PW) {
      float lg[NE];
      #pragma unroll
      for (int e = 0; e < NE; ++e)
        lg[e] = part[0][tid][e] + part[1][tid][e] + part[2][tid][e] + part[3][tid][e];
      int e0 = 0; float l0 = lg[0];
      #pragma unroll
      for (int e = 1; e < NE; ++e) if (lg[e] > l0) { l0 = lg[e]; e0 = e; }
      int e1 = -1; float l1 = -3.4e38f;
      #pragma unroll
      for (int e = 0; e < NE; ++e) if (e != e0 && lg[e] > l1) { l1 = lg[e]; e1 = e; }
      const float p1  = __expf(l1 - l0);
      const float inv = 1.f / (1.f + p1);
      const float g0 = 0.5f * inv, g1 = 0.5f * p1 * inv;   // ADAPTER_SCALE folded
      float g[NE];
      #pragma unroll
      for (int e = 0; e < NE; ++e) g[e] = (e == e0) ? g0 : ((e == e1) ? g1 : 0.f);
      *(float4*)(sg + (size_t)(t0 + tid) * NE)     = *(float4*)&g[0];
      *(float4*)(sg + (size_t)(t0 + tid) * NE + 4) = *(float4*)&g[4];
    }
  } else {
    const int rr = threadIdx.x >> 2;
    const int cc = (threadIdx.x & 3) * 16;
    const int bx = blockIdx.x - NPREP;
    if (bx < 128) {
      const int e  = bx >> 4;
      const int d0 = (bx & 15) * 64;
      const float* src = Wd + ((size_t)e * DM + d0 + rr) * BOT + cc;
      #pragma unroll
      for (int i = 0; i < 4; ++i) {
        float4 v = *(const float4*)(src + i * 4);
        tl[rr][cc + i * 4 + 0] = f2bf(v.x);
        tl[rr][cc + i * 4 + 1] = f2bf(v.y);
        tl[rr][cc + i * 4 + 2] = f2bf(v.z);
        tl[rr][cc + i * 4 + 3] = f2bf(v.w);
      }
      __syncthreads();
      bf16x8 o0, o1;
      #pragma unroll
      for (int k = 0; k < 8; ++k) o0[k] = (short)tl[cc + k][rr];
      #pragma unroll
      for (int k = 0; k < 8; ++k) o1[k] = (short)tl[cc + 8 + k][rr];
      ushort* dst = WdT + ((size_t)e * BOT + rr) * DM + d0 + cc;
      *(bf16x8*)dst       = o0;
      *(bf16x8*)(dst + 8) = o1;
    } else {
      const int b2 = bx - 128;                 // WuT[d][n], [1024][512]
      const int n0 = (b2 >> 4) * 64;
      const int d0 = (b2 & 15) * 64;
      const float* src = Wu + (size_t)(n0 + rr) * DM + d0 + cc;
      #pragma unroll
      for (int i = 0; i < 4; ++i) {
        float4 v = *(const float4*)(src + i * 4);
        tl[rr][cc + i * 4 + 0] = f2bf(v.x);
        tl[rr][cc + i * 4 + 1] = f2bf(v.y);
        tl[rr][cc + i * 4 + 2] = f2bf(v.z);
        tl[rr][cc + i * 4 + 3] = f2bf(v.w);
      }
      __syncthreads();
      bf16x8 o0, o1;
      #pragma unroll
      for (int k = 0; k < 8; ++k) o0[k] = (short)tl[cc + k][rr];
      #pragma unroll
      for (int k = 0; k < 8; ++k) o1[k] = (short)tl[cc + 8 + k][rr];
      ushort* dst = WuT + (size_t)(d0 + rr) * HD + n0 + cc;
      *(bf16x8*)dst       = o0;
      *(bf16x8*)(dst + 8) = o1;
    }
  }
}

// ---- 128(M)x64(N) bf16 GEMM, C = A @ B^T, BK=64, 3-buf, ONE barrier/step ----
// (R7-proven loop: [vmcnt(6|0); barrier; compute(kt); STAGE(kt+2)].)
// LDS XOR-swizzled both-sides; T5 setprio around MFMA clusters.
// EPI=0: Hout[t][col](ld 512) = bf16(relu(acc+bd[col]) * sg[t][col>>6])
// EPI=1: Cout[t][col](ld 1024) = acc + sum_e sg[t][e]*bu[e][col]  (hoisted)
template <int EPI, int NKT, int NBX>
__global__ __launch_bounds__(256)
void gemm_bt(const ushort* __restrict__ A, const ushort* __restrict__ B,
             const float* __restrict__ sg, const float* __restrict__ bd,
             const float* __restrict__ bu,
             ushort* __restrict__ Hout, float* __restrict__ Cout, int nwg) {
  constexpr int K = NKT * 64;
  __shared__ __attribute__((aligned(16))) ushort sA[3][128 * 64];
  __shared__ __attribute__((aligned(16))) ushort sB[3][64 * 64];
  const int lane = threadIdx.x & 63;
  const int w    = threadIdx.x >> 6;
  const int lb = (blockIdx.x % 8) * (nwg / 8) + blockIdx.x / 8;  // XCD-chunked
  const int tile_m = (lb / NBX) * 128;
  const int tile_n = (lb % NBX) * 64;
  const int wm = (w >> 1) * 64;
  const int wn = (w & 1) * 32;
  const int sr = lane >> 3;
  const int sc = ((lane & 7) * 8) ^ (sr << 3);   // pre-swizzled source col
  const int lr = lane & 15;
  const int kg = lane >> 4;
  const int swz = (lr & 7) << 3;                 // read-side XOR (elems)
  f32x4 acc[4][2] = {};

#define STAGE(buf, kt) do {                                                       \
    const int k0_ = (kt) << 6;                                                    \
    _Pragma("unroll")                                                             \
    for (int c = 0; c < 4; ++c) {                                                 \
      const ushort* ga = A + (size_t)(tile_m + w * 32 + c * 8 + sr) * K + k0_ + sc; \
      __builtin_amdgcn_global_load_lds((const __attribute__((address_space(1))) void*)ga, \
          (__attribute__((address_space(3))) void*)&sA[buf][(w * 32 + c * 8) * 64], 16, 0, 0); \
    }                                                                             \
    _Pragma("unroll")                                                             \
    for (int c = 0; c < 2; ++c) {                                                 \
      const ushort* gb = B + (size_t)(tile_n + w * 16 + c * 8 + sr) * K + k0_ + sc; \
      __builtin_amdgcn_global_load_lds((const __attribute__((address_space(1))) void*)gb, \
          (__attribute__((address_space(3))) void*)&sB[buf][(w * 16 + c * 8) * 64], 16, 0, 0); \
    } } while (0)

  STAGE(0, 0);
  STAGE(1, 1);
  for (int kt = 0; kt < NKT; ++kt) {
    const int cur = kt % 3;
    if (kt + 1 < NKT) asm volatile("s_waitcnt vmcnt(6)" ::: "memory");
    else              asm volatile("s_waitcnt vmcnt(0)" ::: "memory");
    __builtin_amdgcn_s_barrier();
    asm volatile("" ::: "memory");
    #pragma unroll
    for (int s = 0; s < 2; ++s) {
      bf16x8 af[4], bfr[2];
      #pragma unroll
      for (int i = 0; i < 4; ++i)
        af[i] = *(const bf16x8*)&sA[cur][(wm + i * 16 + lr) * 64 + ((s * 32 + kg * 8) ^ swz)];
      #pragma unroll
      for (int j = 0; j < 2; ++j)
        bfr[j] = *(const bf16x8*)&sB[cur][(wn + j * 16 + lr) * 64 + ((s * 32 + kg * 8) ^ swz)];
      __builtin_amdgcn_s_setprio(1);
      #pragma unroll
      for (int i = 0; i < 4; ++i)
        #pragma unroll
        for (int j = 0; j < 2; ++j)
          acc[i][j] = __builtin_amdgcn_mfma_f32_16x16x32_bf16(af[i], bfr[j], acc[i][j], 0, 0, 0);
      __builtin_amdgcn_s_setprio(0);
    }
    asm volatile("" ::: "memory");
    if (kt + 2 < NKT) STAGE((kt + 2) % 3, kt + 2);
  }
#undef STAGE

  if (EPI == 0) {
    const int e = tile_n >> 6;               // 64-col tile spans one expert
    float bdv[2];
    #pragma unroll
    for (int j = 0; j < 2; ++j) bdv[j] = bd[tile_n + wn + j * 16 + lr];
    #pragma unroll
    for (int i = 0; i < 4; ++i) {
      #pragma unroll
      for (int r = 0; r < 4; ++r) {
        const int t = tile_m + wm + i * 16 + kg * 4 + r;
        const float sglv = sg[(size_t)t * NE + e];
        #pragma unroll
        for (int j = 0; j < 2; ++j) {
          float v = fmaxf(acc[i][j][r] + bdv[j], 0.f) * sglv;
          Hout[(size_t)t * HD + tile_n + wn + j * 16 + lr] = f2bf(v);
        }
      }
    }
  } else {
    float buv[NE][2];                        // hoisted bu columns (L2-hot)
    #pragma unroll
    for (int j = 0; j < 2; ++j) {
      const int col = tile_n + wn + j * 16 + lr;
      #pragma unroll
      for (int e = 0; e < NE; ++e) buv[e][j] = bu[(size_t)e * DM + col];
    }
    #pragma unroll
    for (int i = 0; i < 4; ++i) {
      #pragma unroll
      for (int r = 0; r < 4; ++r) {
        const int t = tile_m + wm + i * 16 + kg * 4 + r;
        float4 s0 = *(const float4*)(sg + (size_t)t * NE);
        float4 s1 = *(const float4*)(sg + (size_t)t * NE + 4);
        const float sv[NE] = {s0.x, s0.y, s0.z, s0.w, s1.x, s1.y, s1.z, s1.w};
        #pragma unroll
        for (int j = 0; j < 2; ++j) {
          float bias = 0.f;
          #pragma unroll
          for (int e = 0; e < NE; ++e) bias += sv[e] * buv[e][j];
          Cout[(size_t)t * DM + tile_n + wn + j * 16 + lr] = acc[i][j][r] + bias;
        }
      }
    }
  }
}

extern "C" void kernel_launch(void* const* d_in, const int* in_sizes, int n_in,
                              void* d_out, int out_size, void* d_ws, size_t ws_size,
                              hipStream_t stream) {
  const float* x  = (const float*)d_in[0];
  const float* wg = (const float*)d_in[1];
  // d_in[2] = w_noise: unused (reference gates on clean logits)
  const float* Wd = (const float*)d_in[3];
  const float* bd = (const float*)d_in[4];
  const float* Wu = (const float*)d_in[5];
  const float* bu = (const float*)d_in[6];
  float* out = (float*)d_out;

  char* ws = (char*)d_ws;
  ushort* Xb  = (ushort*)(ws);                      // 16 MB
  ushort* H   = (ushort*)(ws + 16777216);           // 8 MB  [8192][512]
  ushort* WdT = (ushort*)(ws + 25165824);           // 1 MB
  ushort* WuT = (ushort*)(ws + 26214400);           // 1 MB
  float*  sgw = (float*) (ws + 27262976);           // 256 KB

  prep_cvt_kernel<<<dim3(NPREP + 256), dim3(256), 0, stream>>>(
      x, wg, Wd, Wu, Xb, sgw, WdT, WuT);

  // H = sg .* relu(X @ WdT^T + bd):   M=8192 N=512 K=1024 (16 steps)
  gemm_bt<0, 16, 8><<<dim3(512), dim3(256), 0, stream>>>(
      Xb, WdT, sgw, bd, nullptr, H, nullptr, 512);
  // out = H @ WuT^T + sg @ bu:        M=8192 N=1024 K=512 (8 steps)
  gemm_bt<1, 8, 16><<<dim3(1024), dim3(256), 0, stream>>>(
      H, WuT, sgw, nullptr, bu, nullptr, out, 1024);
}

// Round 13
// 49.384 us; speedup vs baseline: 2.1175x; 1.0453x over previous
//
#include <hip/hip_runtime.h>
#include <stdint.h>

#define T_TOK 8192
#define DM    1024
#define NE    8
#define BOT   64
#define HD    512
#define HD2   576   // 512 expert cols + 8 sg cols + 56 zero pad (bias folded into K)
#define PW    8     // tokens per prep block
#define NPREP (T_TOK / PW)   // 1024 prep blocks

typedef __attribute__((ext_vector_type(8))) short bf16x8;
typedef __attribute__((ext_vector_type(4))) short bf16x4;
typedef __attribute__((ext_vector_type(4))) float f32x4;

__device__ __forceinline__ ushort f2bf(float f) {
  union { float f; uint32_t u; } v; v.f = f;
  uint32_t r = (v.u + 0x7fffu + ((v.u >> 16) & 1u)) >> 16;
  return (ushort)r;
}

// ---- merged prep (blocks 0..1023) + weight transposes (1024..1295) ---------
__global__ __launch_bounds__(256, 2)
void prep_cvt_kernel(const float* __restrict__ x, const float* __restrict__ wg,
                     const float* __restrict__ Wd, const float* __restrict__ Wu,
                     const float* __restrict__ bu,
                     ushort* __restrict__ Xb, float* __restrict__ sg,
                     ushort* __restrict__ H2, ushort* __restrict__ WdT,
                     ushort* __restrict__ Wu2T) {
  __shared__ float part[4][PW][NE];
  __shared__ float sgl[PW][NE];
  __shared__ ushort tl[64][72];
  if (blockIdx.x < NPREP) {
    const int lane = threadIdx.x & 63;
    const int w    = threadIdx.x >> 6;
    const int t0   = blockIdx.x * PW;
    const int dd   = w * 256 + lane * 4;
    float4 wgr[4][2];
    #pragma unroll
    for (int j = 0; j < 4; ++j) {
      wgr[j][0] = *(const float4*)(wg + (size_t)(dd + j) * NE);
      wgr[j][1] = *(const float4*)(wg + (size_t)(dd + j) * NE + 4);
      // pin in VGPRs (scalar tied constraints): forbids per-token remat re-loads
      asm volatile("" : "+v"(wgr[j][0].x), "+v"(wgr[j][0].y),
                        "+v"(wgr[j][0].z), "+v"(wgr[j][0].w),
                        "+v"(wgr[j][1].x), "+v"(wgr[j][1].y),
                        "+v"(wgr[j][1].z), "+v"(wgr[j][1].w));
    }
    const int ebit = ((lane & 1) << 2) | (lane & 2) | ((lane >> 2) & 1);
    const float* xp = x + (size_t)t0 * DM + dd;
    float4 xv = *(const float4*)xp;
    #pragma unroll
    for (int tk = 0; tk < PW; ++tk) {
      float4 nxt = {};
      if (tk + 1 < PW) nxt = *(const float4*)(xp + (size_t)(tk + 1) * DM);
      bf16x4 xb;
      xb[0] = (short)f2bf(xv.x); xb[1] = (short)f2bf(xv.y);
      xb[2] = (short)f2bf(xv.z); xb[3] = (short)f2bf(xv.w);
      *(bf16x4*)(Xb + (size_t)(t0 + tk) * DM + dd) = xb;
      float a[NE] = {};
      const float* xs = (const float*)&xv;
      #pragma unroll
      for (int j = 0; j < 4; ++j) {
        const float xj = xs[j];
        const float* wr = (const float*)&wgr[j][0];
        #pragma unroll
        for (int e = 0; e < NE; ++e) a[e] += xj * wr[e];
      }
      float t0v[4];
      #pragma unroll
      for (int j = 0; j < 4; ++j) {
        float send = (lane & 1) ? a[j] : a[j + 4];
        float keep = (lane & 1) ? a[j + 4] : a[j];
        t0v[j] = keep + __shfl_xor(send, 1);
      }
      float t1v[2];
      #pragma unroll
      for (int j = 0; j < 2; ++j) {
        float send = (lane & 2) ? t0v[j] : t0v[j + 2];
        float keep = (lane & 2) ? t0v[j + 2] : t0v[j];
        t1v[j] = keep + __shfl_xor(send, 2);
      }
      {
        float send = (lane & 4) ? t1v[0] : t1v[1];
        float keep = (lane & 4) ? t1v[1] : t1v[0];
        float t2 = keep + __shfl_xor(send, 4);
        t2 += __shfl_xor(t2, 8);
        t2 += __shfl_xor(t2, 16);
        t2 += __shfl_xor(t2, 32);
        if (lane < NE) part[w][tk][ebit] = t2;
      }
      xv = nxt;
    }
    __syncthreads();
    const int tid = threadIdx.x;
    if (tid < PW) {
      float lg[NE];
      #pragma unroll
      for (int e = 0; e < NE; ++e)
        lg[e] = part[0][tid][e] + part[1][tid][e] + part[2][tid][e] + part[3][tid][e];
      int e0 = 0; float l0 = lg[0];
      #pragma unroll
      for (int e = 1; e < NE; ++e) if (lg[e] > l0) { l0 = lg[e]; e0 = e; }
      int e1 = -1; float l1 = -3.4e38f;
      #pragma unroll
      for (int e = 0; e < NE; ++e) if (e != e0 && lg[e] > l1) { l1 = lg[e]; e1 = e; }
      const float p1  = __expf(l1 - l0);
      const float inv = 1.f / (1.f + p1);
      const float g0 = 0.5f * inv, g1 = 0.5f * p1 * inv;   // ADAPTER_SCALE folded
      float g[NE];
      #pragma unroll
      for (int e = 0; e < NE; ++e) g[e] = (e == e0) ? g0 : ((e == e1) ? g1 : 0.f);
      #pragma unroll
      for (int e = 0; e < NE; ++e) sgl[tid][e] = g[e];
      *(float4*)(sg + (size_t)(t0 + tid) * NE)     = *(float4*)&g[0];
      *(float4*)(sg + (size_t)(t0 + tid) * NE + 4) = *(float4*)&g[4];
    }
    __syncthreads();
    if (tid < PW * 8) {
      const int tk = tid >> 3, ch = tid & 7;
      bf16x8 v;
      #pragma unroll
      for (int k = 0; k < 8; ++k)
        v[k] = (ch == 0) ? (short)f2bf(sgl[tk][k]) : (short)0;
      *(bf16x8*)(H2 + (size_t)(t0 + tk) * HD2 + HD + ch * 8) = v;
    }
  } else {
    const int rr = threadIdx.x >> 2;
    const int cc = (threadIdx.x & 3) * 16;
    const int bx = blockIdx.x - NPREP;
    if (bx < 128) {
      const int e  = bx >> 4;
      const int d0 = (bx & 15) * 64;
      const float* src = Wd + ((size_t)e * DM + d0 + rr) * BOT + cc;
      #pragma unroll
      for (int i = 0; i < 4; ++i) {
        float4 v = *(const float4*)(src + i * 4);
        tl[rr][cc + i * 4 + 0] = f2bf(v.x);
        tl[rr][cc + i * 4 + 1] = f2bf(v.y);
        tl[rr][cc + i * 4 + 2] = f2bf(v.z);
        tl[rr][cc + i * 4 + 3] = f2bf(v.w);
      }
      __syncthreads();
      bf16x8 o0, o1;
      #pragma unroll
      for (int k = 0; k < 8; ++k) o0[k] = (short)tl[cc + k][rr];
      #pragma unroll
      for (int k = 0; k < 8; ++k) o1[k] = (short)tl[cc + 8 + k][rr];
      ushort* dst = WdT + ((size_t)e * BOT + rr) * DM + d0 + cc;
      *(bf16x8*)dst       = o0;
      *(bf16x8*)(dst + 8) = o1;
    } else {
      const int b2 = bx - 128;
      const int n0 = (b2 >> 4) * 64;
      const int d0 = (b2 & 15) * 64;
      const int n  = n0 + rr;
      #pragma unroll
      for (int i = 0; i < 4; ++i) {
        float4 v;
        if (n < HD)           v = *(const float4*)(Wu + (size_t)n * DM + d0 + cc + i * 4);
        else if (n < HD + NE) v = *(const float4*)(bu + (size_t)(n - HD) * DM + d0 + cc + i * 4);
        else { v.x = 0.f; v.y = 0.f; v.z = 0.f; v.w = 0.f; }
        tl[rr][cc + i * 4 + 0] = f2bf(v.x);
        tl[rr][cc + i * 4 + 1] = f2bf(v.y);
        tl[rr][cc + i * 4 + 2] = f2bf(v.z);
        tl[rr][cc + i * 4 + 3] = f2bf(v.w);
      }
      __syncthreads();
      bf16x8 o0, o1;
      #pragma unroll
      for (int k = 0; k < 8; ++k) o0[k] = (short)tl[cc + k][rr];
      #pragma unroll
      for (int k = 0; k < 8; ++k) o1[k] = (short)tl[cc + 8 + k][rr];
      ushort* dst = Wu2T + (size_t)(d0 + rr) * HD2 + n0 + cc;
      *(bf16x8*)dst       = o0;
      *(bf16x8*)(dst + 8) = o1;
    }
  }
}

// ---- 128(M)x64(N) bf16 GEMM, C = A @ B^T, 3-buf, ONE barrier per K-step -----
// Loop order: [vmcnt(6|0); barrier; compute(kt); STAGE(kt+2)]  (R7-proven).
// LDS XOR-swizzled both-sides (rule 21); T5 setprio around MFMA clusters.
// EPI=0: Hout[t][col](ld 576) = bf16(relu(acc+bd[col]) * sg[t][col>>6])
// EPI=1: Cout[t][col](ld 1024) = acc   (bias folded into K via H2 tail)
template <int EPI, int NKT, int NBX>
__global__ __launch_bounds__(256)
void gemm_bt(const ushort* __restrict__ A, const ushort* __restrict__ B,
             const float* __restrict__ sg, const float* __restrict__ bd,
             ushort* __restrict__ Hout, float* __restrict__ Cout, int nwg) {
  constexpr int K = NKT * 64;
  __shared__ __attribute__((aligned(16))) ushort sA[3][128 * 64];
  __shared__ __attribute__((aligned(16))) ushort sB[3][64 * 64];
  const int lane = threadIdx.x & 63;
  const int w    = threadIdx.x >> 6;
  const int lb = (blockIdx.x % 8) * (nwg / 8) + blockIdx.x / 8;  // XCD-chunked
  const int tile_m = (lb / NBX) * 128;
  const int tile_n = (lb % NBX) * 64;
  const int wm = (w >> 1) * 64;
  const int wn = (w & 1) * 32;
  const int sr = lane >> 3;
  const int sc = ((lane & 7) * 8) ^ (sr << 3);   // pre-swizzled source col
  const int lr = lane & 15;
  const int kg = lane >> 4;
  const int swz = (lr & 7) << 3;                 // read-side XOR (elems)
  f32x4 acc[4][2] = {};

#define STAGE(buf, kt) do {                                                       \
    const int k0_ = (kt) << 6;                                                    \
    _Pragma("unroll")                                                             \
    for (int c = 0; c < 4; ++c) {                                                 \
      const ushort* ga = A + (size_t)(tile_m + w * 32 + c * 8 + sr) * K + k0_ + sc; \
      __builtin_amdgcn_global_load_lds((const __attribute__((address_space(1))) void*)ga, \
          (__attribute__((address_space(3))) void*)&sA[buf][(w * 32 + c * 8) * 64], 16, 0, 0); \
    }                                                                             \
    _Pragma("unroll")                                                             \
    for (int c = 0; c < 2; ++c) {                                                 \
      const ushort* gb = B + (size_t)(tile_n + w * 16 + c * 8 + sr) * K + k0_ + sc; \
      __builtin_amdgcn_global_load_lds((const __attribute__((address_space(1))) void*)gb, \
          (__attribute__((address_space(3))) void*)&sB[buf][(w * 16 + c * 8) * 64], 16, 0, 0); \
    } } while (0)

  STAGE(0, 0);
  STAGE(1, 1);
  for (int kt = 0; kt < NKT; ++kt) {
    const int cur = kt % 3;
    if (kt + 1 < NKT) asm volatile("s_waitcnt vmcnt(6)" ::: "memory");
    else              asm volatile("s_waitcnt vmcnt(0)" ::: "memory");
    __builtin_amdgcn_s_barrier();
    asm volatile("" ::: "memory");
    #pragma unroll
    for (int s = 0; s < 2; ++s) {
      bf16x8 af[4], bfr[2];
      #pragma unroll
      for (int i = 0; i < 4; ++i)
        af[i] = *(const bf16x8*)&sA[cur][(wm + i * 16 + lr) * 64 + ((s * 32 + kg * 8) ^ swz)];
      #pragma unroll
      for (int j = 0; j < 2; ++j)
        bfr[j] = *(const bf16x8*)&sB[cur][(wn + j * 16 + lr) * 64 + ((s * 32 + kg * 8) ^ swz)];
      __builtin_amdgcn_s_setprio(1);
      #pragma unroll
      for (int i = 0; i < 4; ++i)
        #pragma unroll
        for (int j = 0; j < 2; ++j)
          acc[i][j] = __builtin_amdgcn_mfma_f32_16x16x32_bf16(af[i], bfr[j], acc[i][j], 0, 0, 0);
      __builtin_amdgcn_s_setprio(0);
    }
    asm volatile("" ::: "memory");
    if (kt + 2 < NKT) STAGE((kt + 2) % 3, kt + 2);
  }
#undef STAGE

  if (EPI == 0) {
    const int e = tile_n >> 6;               // 64-col tile spans one expert
    float bdv[2];
    #pragma unroll
    for (int j = 0; j < 2; ++j) bdv[j] = bd[tile_n + wn + j * 16 + lr];
    #pragma unroll
    for (int i = 0; i < 4; ++i) {
      #pragma unroll
      for (int r = 0; r < 4; ++r) {
        const int t = tile_m + wm + i * 16 + kg * 4 + r;
        const float sglv = sg[(size_t)t * NE + e];
        #pragma unroll
        for (int j = 0; j < 2; ++j) {
          float v = fmaxf(acc[i][j][r] + bdv[j], 0.f) * sglv;
          Hout[(size_t)t * HD2 + tile_n + wn + j * 16 + lr] = f2bf(v);
        }
      }
    }
  } else {
    #pragma unroll
    for (int i = 0; i < 4; ++i) {
      #pragma unroll
      for (int r = 0; r < 4; ++r) {
        const int t = tile_m + wm + i * 16 + kg * 4 + r;
        #pragma unroll
        for (int j = 0; j < 2; ++j)
          Cout[(size_t)t * DM + tile_n + wn + j * 16 + lr] = acc[i][j][r];
      }
    }
  }
}

extern "C" void kernel_launch(void* const* d_in, const int* in_sizes, int n_in,
                              void* d_out, int out_size, void* d_ws, size_t ws_size,
                              hipStream_t stream) {
  const float* x  = (const float*)d_in[0];
  const float* wg = (const float*)d_in[1];
  // d_in[2] = w_noise: unused (reference gates on clean logits)
  const float* Wd = (const float*)d_in[3];
  const float* bd = (const float*)d_in[4];
  const float* Wu = (const float*)d_in[5];
  const float* bu = (const float*)d_in[6];
  float* out = (float*)d_out;

  char* ws = (char*)d_ws;
  ushort* Xb   = (ushort*)(ws);                      // 16 MB
  ushort* H2   = (ushort*)(ws + 16777216);           // 9.44 MB
  ushort* WdT  = (ushort*)(ws + 26214400);           // 1 MB
  ushort* Wu2T = (ushort*)(ws + 27262976);           // 1.18 MB
  float*  sgw  = (float*) (ws + 28442624);           // 256 KB

  prep_cvt_kernel<<<dim3(NPREP + 272), dim3(256), 0, stream>>>(
      x, wg, Wd, Wu, bu, Xb, sgw, H2, WdT, Wu2T);

  // H2[:, :512] = sg .* relu(X @ WdT^T + bd):  M=8192 N=512 K=1024 (16 steps)
  gemm_bt<0, 16, 8><<<dim3(512), dim3(256), 0, stream>>>(
      Xb, WdT, sgw, bd, H2, nullptr, 512);
  // out = H2 @ Wu2T^T (bias folded):           M=8192 N=1024 K=576 (9 steps)
  gemm_bt<1, 9, 16><<<dim3(1024), dim3(256), 0, stream>>>(
      H2, Wu2T, sgw, nullptr, nullptr, out, 1024);
}